// Round 3
// baseline (450.082 us; speedup 1.0000x reference)
//
#include <hip/hip_runtime.h>
#include <hip/hip_bf16.h>
#include <math.h>

typedef _Float16 f16;
typedef _Float16 f16x4 __attribute__((ext_vector_type(4)));
typedef _Float16 f16x8 __attribute__((ext_vector_type(8)));
typedef float f32x4 __attribute__((ext_vector_type(4)));

#define HD 64
#define NH 16
#define BATCH 2
#define SEQ 2048
#define DMODEL 1024
#define NQKV 3072
#define ROWS 4096
#define NEG_BIG (-1.0e30f)
// 0.125 * log2(e): softmax done in base-2 domain (v_exp_f32 is 2^x native)
#define SCALE_LOG2E 0.18033688011112042f

__device__ __forceinline__ f32x4 mfma16h(f16x8 a, f16x8 b, f32x4 c){
  return __builtin_amdgcn_mfma_f32_16x16x32_f16(a, b, c, 0, 0, 0);
}

// global -> LDS async copy, 16B per lane, dest = wave-uniform base + lane*16
__device__ __forceinline__ void gload16(const f16* g, f16* l){
  __builtin_amdgcn_global_load_lds(
      (const __attribute__((address_space(1))) unsigned int*)(g),
      (__attribute__((address_space(3))) unsigned int*)(l), 16, 0, 0);
}

// ---------------- LayerNorm: fp32 in, f16 out (float4 vectorized) ----------
__global__ __launch_bounds__(256) void ln_kernel(const float* __restrict__ x,
    const float* __restrict__ gamma, const float* __restrict__ beta,
    f16* __restrict__ xn)
{
  int row = blockIdx.x;
  int tid = threadIdx.x;
  float4 v = ((const float4*)(x + (size_t)row * DMODEL))[tid];
  float s  = v.x + v.y + v.z + v.w;
  float s2 = v.x*v.x + v.y*v.y + v.z*v.z + v.w*v.w;
  #pragma unroll
  for (int off = 32; off; off >>= 1){ s += __shfl_xor(s, off); s2 += __shfl_xor(s2, off); }
  __shared__ float red[8];
  int wave = tid >> 6, lane = tid & 63;
  if (lane == 0){ red[wave] = s; red[4 + wave] = s2; }
  __syncthreads();
  s  = red[0] + red[1] + red[2] + red[3];
  s2 = red[4] + red[5] + red[6] + red[7];
  float mu  = s * (1.f / DMODEL);
  float var = s2 * (1.f / DMODEL) - mu * mu;
  float rs  = rsqrtf(var + 1e-5f);
  float4 g  = ((const float4*)gamma)[tid];
  float4 be = ((const float4*)beta)[tid];
  f16x4 o;
  o[0] = (f16)((v.x - mu) * rs * g.x + be.x);
  o[1] = (f16)((v.y - mu) * rs * g.y + be.y);
  o[2] = (f16)((v.z - mu) * rs * g.z + be.z);
  o[3] = (f16)((v.w - mu) * rs * g.w + be.w);
  *(f16x4*)(xn + (size_t)row * DMODEL + tid*4) = o;
}

// ------------- Transpose fp32 RxC -> f16 CxR -------------
__global__ __launch_bounds__(256) void transpose_f2h_kernel(const float* __restrict__ in,
    f16* __restrict__ out, int R, int C)
{
  __shared__ float t[32][33];
  int c0 = blockIdx.x * 32, r0 = blockIdx.y * 32;
  int lx = threadIdx.x & 31, ly = threadIdx.x >> 5;
  #pragma unroll
  for (int i = 0; i < 32; i += 8) t[ly + i][lx] = in[(size_t)(r0 + ly + i) * C + c0 + lx];
  __syncthreads();
  #pragma unroll
  for (int i = 0; i < 32; i += 8) out[(size_t)(c0 + ly + i) * R + r0 + lx] = (f16)t[lx][ly + i];
}

// ---------------- QKV GEMM: A[4096,1024]f16 x Bt[3072,1024]f16 -> scatter QKV
__global__ __launch_bounds__(256, 3) void gemm_qkv(const f16* __restrict__ A,
    const f16* __restrict__ Bt, f16* __restrict__ Qo, f16* __restrict__ Ko,
    f16* __restrict__ Vo)
{
  __shared__ __align__(16) f16 As[2][128][32];
  __shared__ __align__(16) f16 Bs[2][128][32];
  const int K = DMODEL;
  int bm = blockIdx.y * 128, bn = blockIdx.x * 128;
  int tid = threadIdx.x;
  int wave = tid >> 6, lane = tid & 63, quad = lane >> 4, l15 = lane & 15;
  int mw = (wave >> 1) * 64, nw = (wave & 1) * 64;

  int sr0 = wave*16 + (lane >> 2);          // rows 0..63
  int sr1 = sr0 + 64;                       // rows 64..127 (same &3)
  int sc  = (lane & 3) ^ (sr0 & 3);         // inverse-swizzled source chunk
  const f16* Ag = A  + (size_t)bm * K;
  const f16* Bg = Bt + (size_t)bn * K;
  f16* ldsA0 = &As[0][wave*16     ][0];
  f16* ldsA1 = &As[0][wave*16 + 64][0];
  f16* ldsB0 = &Bs[0][wave*16     ][0];
  f16* ldsB1 = &Bs[0][wave*16 + 64][0];

#define QSTAGE(buf, k0) do{ \
    gload16(Ag + (size_t)sr0 * K + (k0) + sc*8, ldsA0 + (buf)*4096); \
    gload16(Ag + (size_t)sr1 * K + (k0) + sc*8, ldsA1 + (buf)*4096); \
    gload16(Bg + (size_t)sr0 * K + (k0) + sc*8, ldsB0 + (buf)*4096); \
    gload16(Bg + (size_t)sr1 * K + (k0) + sc*8, ldsB1 + (buf)*4096); }while(0)

  f32x4 zero = {0.f, 0.f, 0.f, 0.f};
  f32x4 acc[4][4];
  #pragma unroll
  for (int i = 0; i < 4; i++)
    #pragma unroll
    for (int j = 0; j < 4; j++) acc[i][j] = zero;

  QSTAGE(0, 0);
  const int NS = K / 32;
  for (int it = 0; it < NS; ++it){
    int cur = it & 1;
    asm volatile("s_waitcnt vmcnt(0)" ::: "memory");
    __syncthreads();
    if (it + 1 < NS) QSTAGE(cur ^ 1, (it + 1) * 32);
    int ca = (quad ^ (l15 & 3)) * 8;
    f16x8 af[4], bfr[4];
    #pragma unroll
    for (int i = 0; i < 4; i++) af[i]  = *(const f16x8*)&As[cur][mw + i*16 + l15][ca];
    #pragma unroll
    for (int i = 0; i < 4; i++) bfr[i] = *(const f16x8*)&Bs[cur][nw + i*16 + l15][ca];
    __builtin_amdgcn_s_setprio(1);
    #pragma unroll
    for (int mi = 0; mi < 4; mi++)
      #pragma unroll
      for (int ni = 0; ni < 4; ni++)
        acc[mi][ni] = mfma16h(af[mi], bfr[ni], acc[mi][ni]);
    __builtin_amdgcn_s_setprio(0);
  }
#undef QSTAGE

  #pragma unroll
  for (int mi = 0; mi < 4; mi++){
    #pragma unroll
    for (int ni = 0; ni < 4; ni++){
      #pragma unroll
      for (int reg = 0; reg < 4; reg++){
        int r = bm + mw + mi*16 + quad*4 + reg;
        int c = bn + nw + ni*16 + l15;
        float v = acc[mi][ni][reg];
        int which = c >> 10;
        int hc = c & 1023;
        int h = hc >> 6, d = hc & 63;
        int b = r >> 11, nseq = r & 2047;
        size_t bh = (size_t)(b * NH + h);
        if (which == 0)      Qo[(bh * SEQ + nseq) * HD + d] = (f16)v;
        else if (which == 1) Ko[(bh * SEQ + nseq) * HD + d] = (f16)v;
        else                 Vo[(bh * HD + d) * SEQ + nseq] = (f16)v;   // V transposed
      }
    }
  }
}

// ---------------- Out GEMM: BM=64, BN=128 -> 512 blocks (2/CU), fp32 store --
__global__ __launch_bounds__(256, 4) void gemm_out(const f16* __restrict__ A,
    const f16* __restrict__ Bt, float* __restrict__ C, int M, int N, int K)
{
  __shared__ __align__(16) f16 As[2][64][32];
  __shared__ __align__(16) f16 Bs[2][128][32];
  int bm = blockIdx.y * 64, bn = blockIdx.x * 128;
  int tid = threadIdx.x;
  int wave = tid >> 6, lane = tid & 63, quad = lane >> 4, l15 = lane & 15;
  int mw = (wave >> 1) * 32, nw = (wave & 1) * 64;

  int sr0 = wave*16 + (lane >> 2);          // 0..63
  int sc  = (lane & 3) ^ (sr0 & 3);
  const f16* Ag = A  + (size_t)bm * K;
  const f16* Bg = Bt + (size_t)bn * K;
  f16* ldsA0 = &As[0][wave*16     ][0];
  f16* ldsB0 = &Bs[0][wave*16     ][0];
  f16* ldsB1 = &Bs[0][wave*16 + 64][0];

#define OSTAGE(buf, k0) do{ \
    gload16(Ag + (size_t)sr0 * K + (k0) + sc*8, ldsA0 + (buf)*2048); \
    gload16(Bg + (size_t)sr0 * K + (k0) + sc*8, ldsB0 + (buf)*4096); \
    gload16(Bg + (size_t)(sr0 + 64) * K + (k0) + sc*8, ldsB1 + (buf)*4096); }while(0)

  f32x4 zero = {0.f, 0.f, 0.f, 0.f};
  f32x4 acc[2][4];
  #pragma unroll
  for (int i = 0; i < 2; i++)
    #pragma unroll
    for (int j = 0; j < 4; j++) acc[i][j] = zero;

  OSTAGE(0, 0);
  const int NS = DMODEL / 32;
  for (int it = 0; it < NS; ++it){
    int cur = it & 1;
    asm volatile("s_waitcnt vmcnt(0)" ::: "memory");
    __syncthreads();
    if (it + 1 < NS) OSTAGE(cur ^ 1, (it + 1) * 32);
    int ca = (quad ^ (l15 & 3)) * 8;
    f16x8 af[2], bfr[4];
    #pragma unroll
    for (int i = 0; i < 2; i++) af[i]  = *(const f16x8*)&As[cur][mw + i*16 + l15][ca];
    #pragma unroll
    for (int i = 0; i < 4; i++) bfr[i] = *(const f16x8*)&Bs[cur][nw + i*16 + l15][ca];
    __builtin_amdgcn_s_setprio(1);
    #pragma unroll
    for (int mi = 0; mi < 2; mi++)
      #pragma unroll
      for (int ni = 0; ni < 4; ni++)
        acc[mi][ni] = mfma16h(af[mi], bfr[ni], acc[mi][ni]);
    __builtin_amdgcn_s_setprio(0);
  }
#undef OSTAGE

  #pragma unroll
  for (int mi = 0; mi < 2; mi++)
    #pragma unroll
    for (int ni = 0; ni < 4; ni++)
      #pragma unroll
      for (int reg = 0; reg < 4; reg++){
        int r = bm + mw + mi*16 + quad*4 + reg;
        int c = bn + nw + ni*16 + l15;
        C[(size_t)r * N + c] = acc[mi][ni][reg];
      }
}

// ---------------- Flash attention: dots = (QK^T + m) * SCALE ----
// BARRIER-FREE: K/V fragments loaded DIRECTLY global->VGPR (L2/L3-resident,
// 16B/lane contiguous); software-pipelined (V at iter top, next-K right after
// QK consumes current K). LDS only for the per-wave 8KB P-transpose slab
// (same-wave write/read -> no __syncthreads anywhere). Sum-reduce deferred to
// epilogue (linear); only row-max needs 2 shuffles per tile.
__global__ __launch_bounds__(256, 3) void attn_kernel(const f16* __restrict__ Q,
    const f16* __restrict__ Kb, const f16* __restrict__ Vt,
    const float* __restrict__ mask, f16* __restrict__ Ao)
{
  __shared__ __align__(16) f16 Ps[4*16*64];

  int bh = blockIdx.y; int b = bh >> 4; int h = bh & 15;
  int q0 = blockIdx.x * 64;
  int tid = threadIdx.x;
  int wave = tid >> 6, lane = tid & 63, quad = lane >> 4, l15 = lane & 15;

  const f16* Kg = Kb + (size_t)bh * SEQ * HD;
  const f16* Vg = Vt + (size_t)bh * HD * SEQ;

  // Q fragments: loop-invariant
  f16x8 qf[2];
  {
    const f16* qrow = Q + ((size_t)bh * SEQ + q0 + wave*16 + l15) * HD + quad*8;
    qf[0] = *(const f16x8*)(qrow);
    qf[1] = *(const f16x8*)(qrow + 32);
  }

  // per-thread mask row (i = wave*16 + l15), col offset quad*4
  const float* mrow = mask + ((size_t)b * SEQ + q0 + wave*16 + l15) * SEQ + quad*4;

  f32x4 zero = {0.f, 0.f, 0.f, 0.f};
  f32x4 O[4];
  #pragma unroll
  for (int nt = 0; nt < 4; nt++) O[nt] = zero;
  float mrun = NEG_BIG, lrun = 0.f;

  // K fragments for tile 0 (kf[jt*2+kk]: lane holds K[j0+jt*16+l15][kk*32+quad*8..])
  f16x8 kf[8];
  #pragma unroll
  for (int jt = 0; jt < 4; jt++)
    #pragma unroll
    for (int kk = 0; kk < 2; kk++)
      kf[jt*2+kk] = *(const f16x8*)(Kg + (size_t)(jt*16 + l15)*HD + kk*32 + quad*8);

  const int NT = SEQ / 64;
  #pragma unroll 1
  for (int it = 0; it < NT; ++it){
    int j0 = it * 64;
    int jn = (j0 + 64) & (SEQ - 1);   // next tile (wraps harmlessly on last iter)

    // V fragments tile it (vf[nt*2+kk]: lane holds Vt[nt*16+l15][j0+kk*32+quad*8..])
    f16x8 vf[8];
    #pragma unroll
    for (int nt = 0; nt < 4; nt++)
      #pragma unroll
      for (int kk = 0; kk < 2; kk++)
        vf[nt*2+kk] = *(const f16x8*)(Vg + (size_t)(nt*16 + l15)*SEQ + j0 + kk*32 + quad*8);

    // mask tile it
    float4 mv[4];
    #pragma unroll
    for (int jt = 0; jt < 4; jt++) mv[jt] = *(const float4*)(mrow + j0 + jt*16);

    // ---- QK^T (swapped) + mask, base-2 scaled domain ----
    float sv[4][4];   // [jt][reg]: S[i=l15][j = j0 + jt*16 + quad*4 + reg]
    __builtin_amdgcn_s_setprio(1);
    #pragma unroll
    for (int jt = 0; jt < 4; jt++){
      f32x4 a = zero;
      a = mfma16h(kf[jt*2 + 0], qf[0], a);
      a = mfma16h(kf[jt*2 + 1], qf[1], a);
      sv[jt][0] = (a[0] + mv[jt].x) * SCALE_LOG2E;
      sv[jt][1] = (a[1] + mv[jt].y) * SCALE_LOG2E;
      sv[jt][2] = (a[2] + mv[jt].z) * SCALE_LOG2E;
      sv[jt][3] = (a[3] + mv[jt].w) * SCALE_LOG2E;
    }
    __builtin_amdgcn_s_setprio(0);

    // prefetch K fragments for tile it+1 (anti-dep on QK keeps order; latency
    // hidden under softmax + PV)
    #pragma unroll
    for (int jt = 0; jt < 4; jt++)
      #pragma unroll
      for (int kk = 0; kk < 2; kk++)
        kf[jt*2+kk] = *(const f16x8*)(Kg + (size_t)(jn + jt*16 + l15)*HD + kk*32 + quad*8);

    // ---- row max (in-thread tree + 2 shfl) ----
    float m0 = fmaxf(fmaxf(sv[0][0], sv[0][1]), fmaxf(sv[0][2], sv[0][3]));
    float m1 = fmaxf(fmaxf(sv[1][0], sv[1][1]), fmaxf(sv[1][2], sv[1][3]));
    float m2 = fmaxf(fmaxf(sv[2][0], sv[2][1]), fmaxf(sv[2][2], sv[2][3]));
    float m3 = fmaxf(fmaxf(sv[3][0], sv[3][1]), fmaxf(sv[3][2], sv[3][3]));
    float tmax = fmaxf(fmaxf(m0, m1), fmaxf(m2, m3));
    tmax = fmaxf(tmax, __shfl_xor(tmax, 16));
    tmax = fmaxf(tmax, __shfl_xor(tmax, 32));

    // ---- defer-max rescale (THR = 8 in log2 domain -> P <= 256, f16-safe) ----
    if (__any(tmax > mrun + 8.f)){
      float nm = fmaxf(mrun, tmax);
      float alpha = exp2f(mrun - nm);
      mrun = nm;
      lrun *= alpha;                      // alpha row-uniform -> per-quad partial ok
      float aR[4];
      #pragma unroll
      for (int reg = 0; reg < 4; reg++)
        aR[reg] = __shfl(alpha, (lane & 48) | (quad*4 + reg));
      #pragma unroll
      for (int nt = 0; nt < 4; nt++)
        #pragma unroll
        for (int reg = 0; reg < 4; reg++) O[nt][reg] *= aR[reg];
    }

    // ---- exp + per-thread partial sum (cross-quad combine deferred) ----
    float ps = 0.f;
    #pragma unroll
    for (int jt = 0; jt < 4; jt++)
      #pragma unroll
      for (int reg = 0; reg < 4; reg++){
        float p = exp2f(sv[jt][reg] - mrun);
        sv[jt][reg] = p; ps += p;
      }
    lrun += ps;

    // ---- P -> LDS transpose slab (same-wave: no barrier) ----
    #pragma unroll
    for (int jt = 0; jt < 4; jt++){
      f16x4 ph;
      ph[0] = (f16)sv[jt][0]; ph[1] = (f16)sv[jt][1];
      ph[2] = (f16)sv[jt][2]; ph[3] = (f16)sv[jt][3];
      *(f16x4*)&Ps[wave*1024 + l15*64 + (((jt*2 + (quad>>1)) ^ (l15 & 7))*8) + (quad & 1)*4] = ph;
    }
    f16x8 pf0 = *(const f16x8*)&Ps[wave*1024 + l15*64 + (((0*4 + quad) ^ (l15 & 7))*8)];
    f16x8 pf1 = *(const f16x8*)&Ps[wave*1024 + l15*64 + (((1*4 + quad) ^ (l15 & 7))*8)];

    // ---- PV ----
    __builtin_amdgcn_s_setprio(1);
    #pragma unroll
    for (int nt = 0; nt < 4; nt++){
      O[nt] = mfma16h(pf0, vf[nt*2 + 0], O[nt]);
      O[nt] = mfma16h(pf1, vf[nt*2 + 1], O[nt]);
    }
    __builtin_amdgcn_s_setprio(0);
  }

  // ---- epilogue: combine per-quad partial sums, redistribute, store ----
  lrun += __shfl_xor(lrun, 16);
  lrun += __shfl_xor(lrun, 32);
  float lR[4];
  #pragma unroll
  for (int reg = 0; reg < 4; reg++)
    lR[reg] = __shfl(lrun, (lane & 48) | (quad*4 + reg));
  #pragma unroll
  for (int nt = 0; nt < 4; nt++){
    #pragma unroll
    for (int reg = 0; reg < 4; reg++){
      float o = O[nt][reg] / lR[reg];
      int r = q0 + wave*16 + quad*4 + reg;
      Ao[((size_t)(b * SEQ + r)) * DMODEL + h * HD + nt*16 + l15] = (f16)o;
    }
  }
}

// ---------------- launch ----------------
// OUTPUT IS FP32. ws (>=48 MiB verified by probe):
//   xn f16 @0 (Ao alias after QKV) | Qb @8M (WoutT alias after attn)
//   Kb @16M | Vt @24M | WqkvT @32M (6MB)
extern "C" void kernel_launch(void* const* d_in, const int* in_sizes, int n_in,
                              void* d_out, int out_size, void* d_ws, size_t ws_size,
                              hipStream_t stream)
{
  (void)in_sizes; (void)n_in; (void)out_size; (void)ws_size;
  const float* x     = (const float*)d_in[0];
  const float* m     = (const float*)d_in[1];
  const float* gamma = (const float*)d_in[2];
  const float* beta  = (const float*)d_in[3];
  const float* Wqkv  = (const float*)d_in[4];
  const float* Wout  = (const float*)d_in[5];
  float* out = (float*)d_out;

  char* ws = (char*)d_ws;
  f16* xn    = (f16*)(ws + 0);
  f16* Ao    = (f16*)(ws + 0);            // alias: xn dead after gemm_qkv
  f16* Qb    = (f16*)(ws + 8388608);
  f16* WoutT = (f16*)(ws + 8388608);      // alias: Qb dead after attn
  f16* Kbuf  = (f16*)(ws + 16777216);
  f16* Vtb   = (f16*)(ws + 25165824);
  f16* WqkvT = (f16*)(ws + 33554432);

  ln_kernel<<<ROWS, 256, 0, stream>>>(x, gamma, beta, xn);
  transpose_f2h_kernel<<<dim3(NQKV/32, DMODEL/32), 256, 0, stream>>>(Wqkv, WqkvT, DMODEL, NQKV);
  gemm_qkv<<<dim3(NQKV/128, ROWS/128), 256, 0, stream>>>(xn, WqkvT, Qb, Kbuf, Vtb);
  attn_kernel<<<dim3(SEQ/64, BATCH*NH), 256, 0, stream>>>(Qb, Kbuf, Vtb, m, Ao);
  transpose_f2h_kernel<<<dim3(DMODEL/32, DMODEL/32), 256, 0, stream>>>(Wout, WoutT, DMODEL, DMODEL);
  gemm_out<<<dim3(DMODEL/128, ROWS/64), 256, 0, stream>>>(Ao, WoutT, out, ROWS, DMODEL, DMODEL);
}

// Round 4
// 253.096 us; speedup vs baseline: 1.7783x; 1.7783x over previous
//
#include <hip/hip_runtime.h>
#include <hip/hip_bf16.h>
#include <math.h>

typedef _Float16 f16;
typedef _Float16 f16x4 __attribute__((ext_vector_type(4)));
typedef _Float16 f16x8 __attribute__((ext_vector_type(8)));
typedef float f32x4 __attribute__((ext_vector_type(4)));

#define HD 64
#define NH 16
#define BATCH 2
#define SEQ 2048
#define DMODEL 1024
#define NQKV 3072
#define ROWS 4096
#define NEG_BIG (-1.0e30f)
// 0.125 * log2(e): softmax done in base-2 domain (v_exp_f32 is 2^x native)
#define SCALE_LOG2E 0.18033688011112042f

__device__ __forceinline__ f32x4 mfma16h(f16x8 a, f16x8 b, f32x4 c){
  return __builtin_amdgcn_mfma_f32_16x16x32_f16(a, b, c, 0, 0, 0);
}

// global -> LDS async copy, 16B per lane, dest = wave-uniform base + lane*16
__device__ __forceinline__ void gload16(const f16* g, f16* l){
  __builtin_amdgcn_global_load_lds(
      (const __attribute__((address_space(1))) unsigned int*)(g),
      (__attribute__((address_space(3))) unsigned int*)(l), 16, 0, 0);
}

// ---------------- LayerNorm: fp32 in, f16 out (float4 vectorized) ----------
__global__ __launch_bounds__(256) void ln_kernel(const float* __restrict__ x,
    const float* __restrict__ gamma, const float* __restrict__ beta,
    f16* __restrict__ xn)
{
  int row = blockIdx.x;
  int tid = threadIdx.x;
  float4 v = ((const float4*)(x + (size_t)row * DMODEL))[tid];
  float s  = v.x + v.y + v.z + v.w;
  float s2 = v.x*v.x + v.y*v.y + v.z*v.z + v.w*v.w;
  #pragma unroll
  for (int off = 32; off; off >>= 1){ s += __shfl_xor(s, off); s2 += __shfl_xor(s2, off); }
  __shared__ float red[8];
  int wave = tid >> 6, lane = tid & 63;
  if (lane == 0){ red[wave] = s; red[4 + wave] = s2; }
  __syncthreads();
  s  = red[0] + red[1] + red[2] + red[3];
  s2 = red[4] + red[5] + red[6] + red[7];
  float mu  = s * (1.f / DMODEL);
  float var = s2 * (1.f / DMODEL) - mu * mu;
  float rs  = rsqrtf(var + 1e-5f);
  float4 g  = ((const float4*)gamma)[tid];
  float4 be = ((const float4*)beta)[tid];
  f16x4 o;
  o[0] = (f16)((v.x - mu) * rs * g.x + be.x);
  o[1] = (f16)((v.y - mu) * rs * g.y + be.y);
  o[2] = (f16)((v.z - mu) * rs * g.z + be.z);
  o[3] = (f16)((v.w - mu) * rs * g.w + be.w);
  *(f16x4*)(xn + (size_t)row * DMODEL + tid*4) = o;
}

// ------------- Transpose fp32 RxC -> f16 CxR -------------
__global__ __launch_bounds__(256) void transpose_f2h_kernel(const float* __restrict__ in,
    f16* __restrict__ out, int R, int C)
{
  __shared__ float t[32][33];
  int c0 = blockIdx.x * 32, r0 = blockIdx.y * 32;
  int lx = threadIdx.x & 31, ly = threadIdx.x >> 5;
  #pragma unroll
  for (int i = 0; i < 32; i += 8) t[ly + i][lx] = in[(size_t)(r0 + ly + i) * C + c0 + lx];
  __syncthreads();
  #pragma unroll
  for (int i = 0; i < 32; i += 8) out[(size_t)(c0 + ly + i) * R + r0 + lx] = (f16)t[lx][ly + i];
}

// ---------------- QKV GEMM: A[4096,1024]f16 x Bt[3072,1024]f16 -> scatter QKV
__global__ __launch_bounds__(256, 3) void gemm_qkv(const f16* __restrict__ A,
    const f16* __restrict__ Bt, f16* __restrict__ Qo, f16* __restrict__ Ko,
    f16* __restrict__ Vo)
{
  __shared__ __align__(16) f16 As[2][128][32];
  __shared__ __align__(16) f16 Bs[2][128][32];
  const int K = DMODEL;
  int bm = blockIdx.y * 128, bn = blockIdx.x * 128;
  int tid = threadIdx.x;
  int wave = tid >> 6, lane = tid & 63, quad = lane >> 4, l15 = lane & 15;
  int mw = (wave >> 1) * 64, nw = (wave & 1) * 64;

  int sr0 = wave*16 + (lane >> 2);          // rows 0..63
  int sr1 = sr0 + 64;                       // rows 64..127 (same &3)
  int sc  = (lane & 3) ^ (sr0 & 3);         // inverse-swizzled source chunk
  const f16* Ag = A  + (size_t)bm * K;
  const f16* Bg = Bt + (size_t)bn * K;
  f16* ldsA0 = &As[0][wave*16     ][0];
  f16* ldsA1 = &As[0][wave*16 + 64][0];
  f16* ldsB0 = &Bs[0][wave*16     ][0];
  f16* ldsB1 = &Bs[0][wave*16 + 64][0];

#define QSTAGE(buf, k0) do{ \
    gload16(Ag + (size_t)sr0 * K + (k0) + sc*8, ldsA0 + (buf)*4096); \
    gload16(Ag + (size_t)sr1 * K + (k0) + sc*8, ldsA1 + (buf)*4096); \
    gload16(Bg + (size_t)sr0 * K + (k0) + sc*8, ldsB0 + (buf)*4096); \
    gload16(Bg + (size_t)sr1 * K + (k0) + sc*8, ldsB1 + (buf)*4096); }while(0)

  f32x4 zero = {0.f, 0.f, 0.f, 0.f};
  f32x4 acc[4][4];
  #pragma unroll
  for (int i = 0; i < 4; i++)
    #pragma unroll
    for (int j = 0; j < 4; j++) acc[i][j] = zero;

  QSTAGE(0, 0);
  const int NS = K / 32;
  for (int it = 0; it < NS; ++it){
    int cur = it & 1;
    asm volatile("s_waitcnt vmcnt(0)" ::: "memory");
    __syncthreads();
    if (it + 1 < NS) QSTAGE(cur ^ 1, (it + 1) * 32);
    int ca = (quad ^ (l15 & 3)) * 8;
    f16x8 af[4], bfr[4];
    #pragma unroll
    for (int i = 0; i < 4; i++) af[i]  = *(const f16x8*)&As[cur][mw + i*16 + l15][ca];
    #pragma unroll
    for (int i = 0; i < 4; i++) bfr[i] = *(const f16x8*)&Bs[cur][nw + i*16 + l15][ca];
    __builtin_amdgcn_s_setprio(1);
    #pragma unroll
    for (int mi = 0; mi < 4; mi++)
      #pragma unroll
      for (int ni = 0; ni < 4; ni++)
        acc[mi][ni] = mfma16h(af[mi], bfr[ni], acc[mi][ni]);
    __builtin_amdgcn_s_setprio(0);
  }
#undef QSTAGE

  #pragma unroll
  for (int mi = 0; mi < 4; mi++){
    #pragma unroll
    for (int ni = 0; ni < 4; ni++){
      int c = bn + nw + ni*16 + l15;
      int which = c >> 10;
      int hc = c & 1023;
      int h = hc >> 6, d = hc & 63;
      if (which == 2){
        // V: 4 regs are 4 consecutive nseq at fixed d -> one f16x4 store
        int r = bm + mw + mi*16 + quad*4;
        int b = r >> 11, nseq = r & 2047;
        size_t bh = (size_t)(b * NH + h);
        f16x4 vv;
        #pragma unroll
        for (int reg = 0; reg < 4; reg++) vv[reg] = (f16)acc[mi][ni][reg];
        *(f16x4*)(Vo + (bh * HD + d) * SEQ + nseq) = vv;
      } else {
        #pragma unroll
        for (int reg = 0; reg < 4; reg++){
          int r = bm + mw + mi*16 + quad*4 + reg;
          float v = acc[mi][ni][reg];
          int b = r >> 11, nseq = r & 2047;
          size_t bh = (size_t)(b * NH + h);
          if (which == 0) Qo[(bh * SEQ + nseq) * HD + d] = (f16)v;
          else            Ko[(bh * SEQ + nseq) * HD + d] = (f16)v;
        }
      }
    }
  }
}

// ---------------- Out GEMM: BM=64, BN=128 -> 512 blocks, fp32 store --------
__global__ __launch_bounds__(256, 4) void gemm_out(const f16* __restrict__ A,
    const f16* __restrict__ Bt, float* __restrict__ C, int M, int N, int K)
{
  __shared__ __align__(16) f16 As[2][64][32];
  __shared__ __align__(16) f16 Bs[2][128][32];
  int bm = blockIdx.y * 64, bn = blockIdx.x * 128;
  int tid = threadIdx.x;
  int wave = tid >> 6, lane = tid & 63, quad = lane >> 4, l15 = lane & 15;
  int mw = (wave >> 1) * 32, nw = (wave & 1) * 64;

  int sr0 = wave*16 + (lane >> 2);          // 0..63
  int sc  = (lane & 3) ^ (sr0 & 3);
  const f16* Ag = A  + (size_t)bm * K;
  const f16* Bg = Bt + (size_t)bn * K;
  f16* ldsA0 = &As[0][wave*16     ][0];
  f16* ldsB0 = &Bs[0][wave*16     ][0];
  f16* ldsB1 = &Bs[0][wave*16 + 64][0];

#define OSTAGE(buf, k0) do{ \
    gload16(Ag + (size_t)sr0 * K + (k0) + sc*8, ldsA0 + (buf)*2048); \
    gload16(Bg + (size_t)sr0 * K + (k0) + sc*8, ldsB0 + (buf)*4096); \
    gload16(Bg + (size_t)(sr0 + 64) * K + (k0) + sc*8, ldsB1 + (buf)*4096); }while(0)

  f32x4 zero = {0.f, 0.f, 0.f, 0.f};
  f32x4 acc[2][4];
  #pragma unroll
  for (int i = 0; i < 2; i++)
    #pragma unroll
    for (int j = 0; j < 4; j++) acc[i][j] = zero;

  OSTAGE(0, 0);
  const int NS = DMODEL / 32;
  for (int it = 0; it < NS; ++it){
    int cur = it & 1;
    asm volatile("s_waitcnt vmcnt(0)" ::: "memory");
    __syncthreads();
    if (it + 1 < NS) OSTAGE(cur ^ 1, (it + 1) * 32);
    int ca = (quad ^ (l15 & 3)) * 8;
    f16x8 af[2], bfr[4];
    #pragma unroll
    for (int i = 0; i < 2; i++) af[i]  = *(const f16x8*)&As[cur][mw + i*16 + l15][ca];
    #pragma unroll
    for (int i = 0; i < 4; i++) bfr[i] = *(const f16x8*)&Bs[cur][nw + i*16 + l15][ca];
    __builtin_amdgcn_s_setprio(1);
    #pragma unroll
    for (int mi = 0; mi < 2; mi++)
      #pragma unroll
      for (int ni = 0; ni < 4; ni++)
        acc[mi][ni] = mfma16h(af[mi], bfr[ni], acc[mi][ni]);
    __builtin_amdgcn_s_setprio(0);
  }
#undef OSTAGE

  #pragma unroll
  for (int mi = 0; mi < 2; mi++)
    #pragma unroll
    for (int ni = 0; ni < 4; ni++)
      #pragma unroll
      for (int reg = 0; reg < 4; reg++){
        int r = bm + mw + mi*16 + quad*4 + reg;
        int c = bn + nw + ni*16 + l15;
        C[(size_t)r * N + c] = acc[mi][ni][reg];
      }
}

// ---------------- Flash attention: dots = (QK^T + m) * SCALE ----
// (R2 structure restored — R3's global->VGPR K/V gather was latency-bound.)
// SWAPPED QK^T: mfma(K, Q) -> thread holds S[i = wave*16+l15][j = jt*16+quad*4+reg]
// => softmax row is lane-local: in-reg tree + 2 shfl_xor(16,32), mask float4,
// P write = 4x ds_write_b64, defer-max (T13, THR=8 in base-2 domain).
// K/V double-buffered gload_lds tiles with XOR swizzle.
// LDS = 16K(K)+16K(V)+8K(Ps) = 40960 -> 4 blocks/CU.
__global__ __launch_bounds__(256, 4) void attn_kernel(const f16* __restrict__ Q,
    const f16* __restrict__ Kb, const f16* __restrict__ Vt,
    const float* __restrict__ mask, f16* __restrict__ Ao)
{
  __shared__ __align__(16) f16 KsB[2][64*64];
  __shared__ __align__(16) f16 VsB[2][64*64];
  __shared__ __align__(16) f16 Ps[4*16*64];

  int bh = blockIdx.y; int b = bh >> 4; int h = bh & 15;
  int q0 = blockIdx.x * 64;
  int tid = threadIdx.x;
  int wave = tid >> 6, lane = tid & 63, quad = lane >> 4, l15 = lane & 15;

  // staging geometry: per wave 2 K-insts + 2 V-insts, each 8 rows x 128B
  int rA = (wave*2 + 0)*8 + (lane >> 3);
  int rB = (wave*2 + 1)*8 + (lane >> 3);
  int cp = lane & 7;
  int ccA = cp ^ (rA & 7);
  int ccB = cp ^ (rB & 7);
  const f16* Kg = Kb + (size_t)bh * SEQ * HD;
  const f16* Vg = Vt + (size_t)bh * HD * SEQ;
  f16* ldsKA = &KsB[0][0] + (wave*2 + 0)*8*64;
  f16* ldsKB = &KsB[0][0] + (wave*2 + 1)*8*64;
  f16* ldsVA = &VsB[0][0] + (wave*2 + 0)*8*64;
  f16* ldsVB = &VsB[0][0] + (wave*2 + 1)*8*64;

  // Q fragments: loop-invariant, straight from global
  f16x8 qf[2];
  {
    const f16* qrow = Q + ((size_t)bh * SEQ + q0 + wave*16 + l15) * HD + quad*8;
    qf[0] = *(const f16x8*)(qrow);
    qf[1] = *(const f16x8*)(qrow + 32);
  }

  // per-thread mask row (i = wave*16 + l15), col offset quad*4
  const float* mrow = mask + ((size_t)b * SEQ + q0 + wave*16 + l15) * SEQ + quad*4;

  // prologue: stage tile 0 into buffer 0
  gload16(Kg + (size_t)(0 + rA)*HD + ccA*8, ldsKA);
  gload16(Kg + (size_t)(0 + rB)*HD + ccB*8, ldsKB);
  gload16(Vg + (size_t)rA*SEQ + 0 + ccA*8, ldsVA);
  gload16(Vg + (size_t)rB*SEQ + 0 + ccB*8, ldsVB);

  f32x4 zero = {0.f, 0.f, 0.f, 0.f};
  f32x4 O[4];
  #pragma unroll
  for (int nt = 0; nt < 4; nt++) O[nt] = zero;
  float mrun = NEG_BIG, lrun = 0.f;

  const int NT = SEQ / 64;
  for (int it = 0; it < NT; ++it){
    int cur = it & 1;
    int j0 = it * 64;
    asm volatile("s_waitcnt vmcnt(0)" ::: "memory");
    __syncthreads();
    if (it + 1 < NT){
      int nb = cur ^ 1;
      int j0n = j0 + 64;
      gload16(Kg + (size_t)(j0n + rA)*HD + ccA*8, ldsKA + nb*4096);
      gload16(Kg + (size_t)(j0n + rB)*HD + ccB*8, ldsKB + nb*4096);
      gload16(Vg + (size_t)rA*SEQ + j0n + ccA*8, ldsVA + nb*4096);
      gload16(Vg + (size_t)rB*SEQ + j0n + ccB*8, ldsVB + nb*4096);
    }
    const f16* Ksc = &KsB[cur][0];
    const f16* Vsc = &VsB[cur][0];

    // ---- QK^T (swapped) + mask, base-2 scaled domain ----
    float sv[4][4];   // [jt][reg]: S[i=l15][j = j0 + jt*16 + quad*4 + reg]
    __builtin_amdgcn_s_setprio(1);
    #pragma unroll
    for (int jt = 0; jt < 4; jt++){
      f32x4 a = zero;
      int r = jt*16 + l15;
      #pragma unroll
      for (int kk = 0; kk < 2; kk++){
        f16x8 kf = *(const f16x8*)&Ksc[r*64 + (((kk*4 + quad) ^ (r & 7))*8)];
        a = mfma16h(kf, qf[kk], a);
      }
      float4 mv = *(const float4*)(mrow + j0 + jt*16);
      sv[jt][0] = (a[0] + mv.x) * SCALE_LOG2E;
      sv[jt][1] = (a[1] + mv.y) * SCALE_LOG2E;
      sv[jt][2] = (a[2] + mv.z) * SCALE_LOG2E;
      sv[jt][3] = (a[3] + mv.w) * SCALE_LOG2E;
    }
    __builtin_amdgcn_s_setprio(0);

    // ---- row max (in-thread tree + 2 shfl) ----
    float m0 = fmaxf(fmaxf(sv[0][0], sv[0][1]), fmaxf(sv[0][2], sv[0][3]));
    float m1 = fmaxf(fmaxf(sv[1][0], sv[1][1]), fmaxf(sv[1][2], sv[1][3]));
    float m2 = fmaxf(fmaxf(sv[2][0], sv[2][1]), fmaxf(sv[2][2], sv[2][3]));
    float m3 = fmaxf(fmaxf(sv[3][0], sv[3][1]), fmaxf(sv[3][2], sv[3][3]));
    float tmax = fmaxf(fmaxf(m0, m1), fmaxf(m2, m3));
    tmax = fmaxf(tmax, __shfl_xor(tmax, 16));
    tmax = fmaxf(tmax, __shfl_xor(tmax, 32));

    // ---- defer-max rescale (THR = 8 in log2 domain -> P <= 256, f16-safe) ----
    if (__any(tmax > mrun + 8.f)){
      float nm = fmaxf(mrun, tmax);
      float alpha = exp2f(mrun - nm);
      mrun = nm;
      lrun *= alpha;
      float aR[4];
      #pragma unroll
      for (int reg = 0; reg < 4; reg++)
        aR[reg] = __shfl(alpha, (lane & 48) | (quad*4 + reg));
      #pragma unroll
      for (int nt = 0; nt < 4; nt++)
        #pragma unroll
        for (int reg = 0; reg < 4; reg++) O[nt][reg] *= aR[reg];
    }

    // ---- exp + per-thread partial sum (cross-quad combine deferred) ----
    float ps = 0.f;
    #pragma unroll
    for (int jt = 0; jt < 4; jt++)
      #pragma unroll
      for (int reg = 0; reg < 4; reg++){
        float p = exp2f(sv[jt][reg] - mrun);
        sv[jt][reg] = p; ps += p;
      }
    lrun += ps;

    // ---- P -> LDS: row i=l15, 4 contiguous j per (jt) -> ds_write_b64 ----
    #pragma unroll
    for (int jt = 0; jt < 4; jt++){
      f16x4 ph;
      ph[0] = (f16)sv[jt][0]; ph[1] = (f16)sv[jt][1];
      ph[2] = (f16)sv[jt][2]; ph[3] = (f16)sv[jt][3];
      *(f16x4*)&Ps[wave*1024 + l15*64 + (((jt*2 + (quad>>1)) ^ (l15 & 7))*8) + (quad & 1)*4] = ph;
    }

    // ---- PV (same-wave Ps slab: no barrier) ----
    __builtin_amdgcn_s_setprio(1);
    #pragma unroll
    for (int nt = 0; nt < 4; nt++){
      #pragma unroll
      for (int kk = 0; kk < 2; kk++){
        int rv = nt*16 + l15;
        f16x8 pf = *(const f16x8*)&Ps[wave*1024 + l15*64 + (((kk*4 + quad) ^ (l15 & 7))*8)];
        f16x8 vf = *(const f16x8*)&Vsc[rv*64 + (((kk*4 + quad) ^ (rv & 7))*8)];
        O[nt] = mfma16h(pf, vf, O[nt]);
      }
    }
    __builtin_amdgcn_s_setprio(0);
  }

  // ---- epilogue: combine per-quad partial sums, redistribute, store ----
  lrun += __shfl_xor(lrun, 16);
  lrun += __shfl_xor(lrun, 32);
  float lR[4];
  #pragma unroll
  for (int reg = 0; reg < 4; reg++)
    lR[reg] = __shfl(lrun, (lane & 48) | (quad*4 + reg));
  #pragma unroll
  for (int nt = 0; nt < 4; nt++){
    #pragma unroll
    for (int reg = 0; reg < 4; reg++){
      float o = O[nt][reg] / lR[reg];
      int r = q0 + wave*16 + quad*4 + reg;
      Ao[((size_t)(b * SEQ + r)) * DMODEL + h * HD + nt*16 + l15] = (f16)o;
    }
  }
}

// ---------------- launch ----------------
// OUTPUT IS FP32. ws (>=48 MiB verified by probe):
//   xn f16 @0 (Ao alias after QKV) | Qb @8M (WoutT alias after attn)
//   Kb @16M | Vt @24M | WqkvT @32M (6MB)
extern "C" void kernel_launch(void* const* d_in, const int* in_sizes, int n_in,
                              void* d_out, int out_size, void* d_ws, size_t ws_size,
                              hipStream_t stream)
{
  (void)in_sizes; (void)n_in; (void)out_size; (void)ws_size;
  const float* x     = (const float*)d_in[0];
  const float* m     = (const float*)d_in[1];
  const float* gamma = (const float*)d_in[2];
  const float* beta  = (const float*)d_in[3];
  const float* Wqkv  = (const float*)d_in[4];
  const float* Wout  = (const float*)d_in[5];
  float* out = (float*)d_out;

  char* ws = (char*)d_ws;
  f16* xn    = (f16*)(ws + 0);
  f16* Ao    = (f16*)(ws + 0);            // alias: xn dead after gemm_qkv
  f16* Qb    = (f16*)(ws + 8388608);
  f16* WoutT = (f16*)(ws + 8388608);      // alias: Qb dead after attn
  f16* Kbuf  = (f16*)(ws + 16777216);
  f16* Vtb   = (f16*)(ws + 25165824);
  f16* WqkvT = (f16*)(ws + 33554432);

  ln_kernel<<<ROWS, 256, 0, stream>>>(x, gamma, beta, xn);
  transpose_f2h_kernel<<<dim3(NQKV/32, DMODEL/32), 256, 0, stream>>>(Wqkv, WqkvT, DMODEL, NQKV);
  gemm_qkv<<<dim3(NQKV/128, ROWS/128), 256, 0, stream>>>(xn, WqkvT, Qb, Kbuf, Vtb);
  attn_kernel<<<dim3(SEQ/64, BATCH*NH), 256, 0, stream>>>(Qb, Kbuf, Vtb, m, Ao);
  transpose_f2h_kernel<<<dim3(DMODEL/32, DMODEL/32), 256, 0, stream>>>(Wout, WoutT, DMODEL, DMODEL);
  gemm_out<<<dim3(DMODEL/128, ROWS/64), 256, 0, stream>>>(Ao, WoutT, out, ROWS, DMODEL, DMODEL);
}